// Round 9
// baseline (1397.194 us; speedup 1.0000x reference)
//
#include <hip/hip_runtime.h>

#define N_NODES 50000
#define N_EDGES 800000
#define N_GRAPHS 500
#define BN_EPS 1e-5f
#define F 256
#define SCAN_BLOCKS ((N_NODES + 255) / 256)   // 196
#define NPART 64                              // stats atomic partitions
#define NCHUNK 8                              // feature chunks (32 feat each)
#define NODES_PER_BLOCK 64                    // 4 waves x 16 node-slots
#define NODE_BLOCKS ((N_NODES + NODES_PER_BLOCK - 1) / NODES_PER_BLOCK)   // 782

typedef short short8 __attribute__((ext_vector_type(8)));
typedef short short4v __attribute__((ext_vector_type(4)));
typedef float f32x4 __attribute__((ext_vector_type(4)));
typedef _Float16 h16x8 __attribute__((ext_vector_type(8)));

// ---------------- degree histogram (4 edges/thread) ----------------
__global__ void k_hist(const int* __restrict__ dst, int* __restrict__ cnt) {
    int e0 = (blockIdx.x * blockDim.x + threadIdx.x) * 4;
    if (e0 >= N_EDGES) return;
    int4 d4 = *reinterpret_cast<const int4*>(&dst[e0]);
    atomicAdd(&cnt[d4.x], 1);
    atomicAdd(&cnt[d4.y], 1);
    atomicAdd(&cnt[d4.z], 1);
    atomicAdd(&cnt[d4.w], 1);
}

__global__ void k_dinv(const int* __restrict__ cnt, float* __restrict__ dinv) {
    int n = blockIdx.x * blockDim.x + threadIdx.x;
    if (n < N_NODES) dinv[n] = rsqrtf((float)cnt[n] + 1.0f);
}

// ---------------- prefix scan ----------------
__global__ void k_scan1(const int* __restrict__ cnt, int* __restrict__ rowptr,
                        int* __restrict__ bsum) {
    __shared__ int s[256];
    int tid = threadIdx.x;
    int i = blockIdx.x * 256 + tid;
    int v = (i < N_NODES) ? cnt[i] : 0;
    s[tid] = v;
    __syncthreads();
    for (int off = 1; off < 256; off <<= 1) {
        int add = (tid >= off) ? s[tid - off] : 0;
        __syncthreads();
        s[tid] += add;
        __syncthreads();
    }
    if (i < N_NODES) rowptr[i] = s[tid] - v;
    if (tid == 255) bsum[blockIdx.x] = s[255];
}

__global__ void k_scan2(int* __restrict__ bsum) {
    __shared__ int s[256];
    int tid = threadIdx.x;
    int v = (tid < SCAN_BLOCKS) ? bsum[tid] : 0;
    s[tid] = v;
    __syncthreads();
    for (int off = 1; off < 256; off <<= 1) {
        int add = (tid >= off) ? s[tid - off] : 0;
        __syncthreads();
        s[tid] += add;
        __syncthreads();
    }
    if (tid < SCAN_BLOCKS) bsum[tid] = s[tid] - v;
}

__global__ void k_scan3(int* __restrict__ rowptr, const int* __restrict__ bsum) {
    int i = blockIdx.x * 256 + threadIdx.x;
    if (i < N_NODES) rowptr[i] += bsum[blockIdx.x];
    if (i == 0) rowptr[N_NODES] = N_EDGES;
}

// ---------------- scatter edges into CSR (4 edges/thread) --------------------
__global__ void k_scatter(const int* __restrict__ src, const int* __restrict__ dst,
                          const float* __restrict__ dinv, int* __restrict__ fillptr,
                          int2* __restrict__ epair) {
    int e0 = (blockIdx.x * blockDim.x + threadIdx.x) * 4;
    if (e0 >= N_EDGES) return;
    int4 s4 = *reinterpret_cast<const int4*>(&src[e0]);
    int4 d4 = *reinterpret_cast<const int4*>(&dst[e0]);
    int ss[4] = {s4.x, s4.y, s4.z, s4.w};
    int dd[4] = {d4.x, d4.y, d4.z, d4.w};
    #pragma unroll
    for (int j = 0; j < 4; ++j) {
        float norm = dinv[ss[j]] * dinv[dd[j]];
        int slot = atomicAdd(&fillptr[dd[j]], 1);
        epair[slot] = make_int2(ss[j], __float_as_int(norm));
    }
}

// ---------------- W1 prepack (no BN): W[K][256] f32 -> [256][K] hi/lo bf16 ---
__global__ void k_pack(const float* __restrict__ W, short* __restrict__ hi,
                       short* __restrict__ lo, int K) {
    int idx = blockIdx.x * 256 + threadIdx.x;
    if (idx >= 256 * K) return;
    int n = idx / K, k = idx - n * K;
    float f = W[(size_t)k * 256 + n];
    unsigned u = __builtin_bit_cast(unsigned, f);
    hi[idx] = (short)(u >> 16);
    float hf = __builtin_bit_cast(float, u & 0xFFFF0000u);
    lo[idx] = (short)(__builtin_bit_cast(unsigned, f - hf) >> 16);
}

// ---------------- BN-finalize + weight fold in one kernel --------------------
__global__ __launch_bounds__(256)
void k_wfold(const float* __restrict__ W, const float* __restrict__ stats,
             const float* __restrict__ gamma, const float* __restrict__ beta,
             short* __restrict__ hi, short* __restrict__ lo,
             float* __restrict__ rowvec) {
    __shared__ float red[256];
    const int n = blockIdx.x;
    const int k = threadIdx.x;
    float s = 0.f, q = 0.f;
    for (int p = 0; p < NPART; ++p) {
        s += stats[(size_t)p * 512 + k];
        q += stats[(size_t)p * 512 + 256 + k];
    }
    float m = s * (1.0f / N_NODES);
    float var = q * (1.0f / N_NODES) - m * m;
    float mulk = gamma[k] * rsqrtf(var + BN_EPS);
    float addk = beta[k] - m * mulk;
    float w = W[(size_t)k * 256 + n];
    float f = w * mulk;
    unsigned u = __builtin_bit_cast(unsigned, f);
    hi[(size_t)n * 256 + k] = (short)(u >> 16);
    float hf = __builtin_bit_cast(float, u & 0xFFFF0000u);
    lo[(size_t)n * 256 + k] = (short)(__builtin_bit_cast(unsigned, f - hf) >> 16);
    red[k] = addk * w;
    __syncthreads();
    for (int off = 128; off > 0; off >>= 1) {
        if (k < off) red[k] += red[k + off];
        __syncthreads();
    }
    if (k == 0) rowvec[n] = red[0];
}

// ---------------- split x (layer-1 input) into bf16 hi/lo -------------------
__global__ void k_splitx(const float* __restrict__ x, short* __restrict__ hi,
                         short* __restrict__ lo) {
    int idx = blockIdx.x * 256 + threadIdx.x;   // over N_NODES*128/4
    if (idx >= N_NODES * 32) return;
    float4 v = reinterpret_cast<const float4*>(x)[idx];
    float vv[4] = {v.x, v.y, v.z, v.w};
    short4v h4, l4;
    #pragma unroll
    for (int j = 0; j < 4; ++j) {
        unsigned u = __builtin_bit_cast(unsigned, vv[j]);
        h4[j] = (short)(u >> 16);
        float hf = __builtin_bit_cast(float, u & 0xFFFF0000u);
        l4[j] = (short)(__builtin_bit_cast(unsigned, vv[j] - hf) >> 16);
    }
    *reinterpret_cast<short4v*>(&hi[(size_t)idx * 4]) = h4;
    *reinterpret_cast<short4v*>(&lo[(size_t)idx * 4]) = l4;
}

// ---------------- split-bf16 MFMA GEMM, double-buffered, 1 barrier/K-step ----
#define BK 32
__global__ __launch_bounds__(256)
void k_gemm_mfma(const short* __restrict__ Ahi, const short* __restrict__ Alo,
                 const short* __restrict__ Bhi, const short* __restrict__ Blo,
                 _Float16* __restrict__ C, int M, int K) {
    __shared__ unsigned As[2][2][128 * 16];
    const int tid  = threadIdx.x;
    const int lane = tid & 63;
    const int w    = tid >> 6;
    const int wr   = (w >> 1) * 64;
    const int wc   = (w & 1) * 64;
    const int bid  = blockIdx.x;
    const int bx   = (bid >> 4) * 8 + (bid & 7);
    const int by   = (bid >> 3) & 1;
    const int brow = bx * 128;
    const int bcol = by * 128;

    f32x4 acc[4][4];
    #pragma unroll
    for (int m = 0; m < 4; ++m)
        #pragma unroll
        for (int n = 0; n < 4; ++n) acc[m][n] = (f32x4){0.f, 0.f, 0.f, 0.f};

    const int lr = tid >> 1;
    const int lk = (tid & 1) * 16;
    const int grow = brow + lr;
    const bool rowok = grow < M;
    const short* Ahp = Ahi + (size_t)grow * K + lk;
    const short* Alp = Alo + (size_t)grow * K + lk;
    const int NS = K / BK;

    uint4 ph0, ph1, pl0, pl1;
    auto load_pf = [&](int s) {
        if (rowok) {
            ph0 = *reinterpret_cast<const uint4*>(Ahp + s * BK);
            ph1 = *reinterpret_cast<const uint4*>(Ahp + s * BK + 8);
            pl0 = *reinterpret_cast<const uint4*>(Alp + s * BK);
            pl1 = *reinterpret_cast<const uint4*>(Alp + s * BK + 8);
        } else {
            ph0 = ph1 = pl0 = pl1 = make_uint4(0, 0, 0, 0);
        }
    };

    const int sw  = (lr >> 1) & 3;
    const int c0  = (tid & 1) * 2;
    const int off0 = lr * 16 + ((c0 ^ sw) << 2);
    const int off1 = lr * 16 + (((c0 + 1) ^ sw) << 2);

    load_pf(0);
    *reinterpret_cast<uint4*>(&As[0][0][off0]) = ph0;
    *reinterpret_cast<uint4*>(&As[0][0][off1]) = ph1;
    *reinterpret_cast<uint4*>(&As[0][1][off0]) = pl0;
    *reinterpret_cast<uint4*>(&As[0][1][off1]) = pl1;

    for (int s = 0; s < NS; ++s) {
        const int cur = s & 1;
        if (s + 1 < NS) load_pf(s + 1);
        __syncthreads();

        short8 bh[4], bl[4];
        const int kb = s * BK + (lane >> 4) * 8;
        #pragma unroll
        for (int n = 0; n < 4; ++n) {
            int col = bcol + wc + n * 16 + (lane & 15);
            bh[n] = *reinterpret_cast<const short8*>(Bhi + (size_t)col * K + kb);
            bl[n] = *reinterpret_cast<const short8*>(Blo + (size_t)col * K + kb);
        }
        #pragma unroll
        for (int m = 0; m < 4; ++m) {
            int row = wr + m * 16 + (lane & 15);
            int c = lane >> 4;
            int sw2 = (row >> 1) & 3;
            const unsigned* ph = &As[cur][0][row * 16 + ((c ^ sw2) << 2)];
            const unsigned* pl = &As[cur][1][row * 16 + ((c ^ sw2) << 2)];
            short8 ah = *reinterpret_cast<const short8*>(ph);
            short8 al = *reinterpret_cast<const short8*>(pl);
            #pragma unroll
            for (int n = 0; n < 4; ++n) {
                acc[m][n] = __builtin_amdgcn_mfma_f32_16x16x32_bf16(ah, bh[n], acc[m][n], 0, 0, 0);
                acc[m][n] = __builtin_amdgcn_mfma_f32_16x16x32_bf16(al, bh[n], acc[m][n], 0, 0, 0);
                acc[m][n] = __builtin_amdgcn_mfma_f32_16x16x32_bf16(ah, bl[n], acc[m][n], 0, 0, 0);
            }
        }
        if (s + 1 < NS) {
            *reinterpret_cast<uint4*>(&As[cur ^ 1][0][off0]) = ph0;
            *reinterpret_cast<uint4*>(&As[cur ^ 1][0][off1]) = ph1;
            *reinterpret_cast<uint4*>(&As[cur ^ 1][1][off0]) = pl0;
            *reinterpret_cast<uint4*>(&As[cur ^ 1][1][off1]) = pl1;
        }
    }

    #pragma unroll
    for (int m = 0; m < 4; ++m) {
        #pragma unroll
        for (int n = 0; n < 4; ++n) {
            int col = bcol + wc + n * 16 + (lane & 15);
            #pragma unroll
            for (int j = 0; j < 4; ++j) {
                int row = brow + wr + m * 16 + (lane >> 4) * 4 + j;
                if (row < M) C[(size_t)row * 256 + col] = (_Float16)acc[m][n][j];
            }
        }
    }
}

// ---------------- feature-chunked aggregation --------------------------------
// Grid = NCHUNK * NODE_BLOCKS; chunk = bid / NODE_BLOCKS (slow-varying ->
// concurrent blocks share a 3.2 MB L2-resident xw chunk).
// Wave = 16 node-slots x 4 lanes; lane owns 8 fp16 features of the chunk.
// MODE 0: h chunk -> hhi/hlo bf16 split + BN stats (shfl-reduced, partitioned).
// MODE 1: h chunk -> hfin fp16 (pooled by k_pool).
template<int MODE>
__global__ __launch_bounds__(256)
void k_agg3(const _Float16* __restrict__ xw, const float* __restrict__ dinv,
            const int* __restrict__ rowptr, const int2* __restrict__ epair,
            const float* __restrict__ bias, const float* __restrict__ rowvec,
            short* __restrict__ hhi, short* __restrict__ hlo,
            _Float16* __restrict__ hfin, float* __restrict__ stats) {
    const int tid   = threadIdx.x;
    const int lane  = tid & 63;
    const int wave  = tid >> 6;
    const int grp   = lane >> 2;          // node slot 0..15
    const int sub   = lane & 3;           // feature quad within chunk
    const int nb    = blockIdx.x % NODE_BLOCKS;
    const int ch    = blockIdx.x / NODE_BLOCKS;    // chunk 0..7
    const int n     = nb * NODES_PER_BLOCK + wave * 16 + grp;
    const int fbase = ch * 32 + sub * 8;           // global feature base
    const int unit  = ch * 4 + sub;                // h16x8 unit within row
    const h16x8* xw8 = reinterpret_cast<const h16x8*>(xw);

    float acc[8];
    #pragma unroll
    for (int j = 0; j < 8; ++j) acc[j] = 0.f;
    const bool valid = (n < N_NODES);

    if (valid) {
        float d = dinv[n];
        float sl = d * d;
        h16x8 sv = xw8[(size_t)n * 32 + unit];
        #pragma unroll
        for (int j = 0; j < 8; ++j) acc[j] = sl * (float)sv[j];
        float wsum = sl;

        const int beg = rowptr[n], end = rowptr[n + 1];
        for (int i = beg; i < end; i += 4) {
            int e[4]; float wv[4];
            #pragma unroll
            for (int k = 0; k < 4; ++k) {
                int idx = i + k;
                bool ok = idx < end;
                int2 p = epair[ok ? idx : (end - 1)];
                e[k]  = p.x;
                wv[k] = ok ? __int_as_float(p.y) : 0.f;
            }
            h16x8 r[4];
            #pragma unroll
            for (int k = 0; k < 4; ++k)
                r[k] = xw8[(size_t)e[k] * 32 + unit];
            #pragma unroll
            for (int k = 0; k < 4; ++k) {
                wsum += wv[k];
                #pragma unroll
                for (int j = 0; j < 8; ++j)
                    acc[j] = fmaf(wv[k], (float)r[k][j], acc[j]);
            }
        }

        float4 b0 = *reinterpret_cast<const float4*>(&bias[fbase]);
        float4 b1 = *reinterpret_cast<const float4*>(&bias[fbase + 4]);
        float4 r0 = *reinterpret_cast<const float4*>(&rowvec[fbase]);
        float4 r1 = *reinterpret_cast<const float4*>(&rowvec[fbase + 4]);
        float bv[8] = {b0.x, b0.y, b0.z, b0.w, b1.x, b1.y, b1.z, b1.w};
        float rv[8] = {r0.x, r0.y, r0.z, r0.w, r1.x, r1.y, r1.z, r1.w};
        #pragma unroll
        for (int j = 0; j < 8; ++j)
            acc[j] = fmaxf(acc[j] + fmaf(wsum, rv[j], bv[j]), 0.f);

        if (MODE == 0) {
            unsigned hw[4], lw[4];
            #pragma unroll
            for (int p = 0; p < 4; ++p) {
                float f0 = acc[2 * p], f1 = acc[2 * p + 1];
                unsigned u0 = __builtin_bit_cast(unsigned, f0);
                unsigned u1 = __builtin_bit_cast(unsigned, f1);
                hw[p] = (u1 & 0xFFFF0000u) | (u0 >> 16);
                float h0 = __builtin_bit_cast(float, u0 & 0xFFFF0000u);
                float h1 = __builtin_bit_cast(float, u1 & 0xFFFF0000u);
                lw[p] = (__builtin_bit_cast(unsigned, f1 - h1) & 0xFFFF0000u) |
                        (__builtin_bit_cast(unsigned, f0 - h0) >> 16);
            }
            *reinterpret_cast<uint4*>(&hhi[(size_t)n * 256 + fbase]) =
                make_uint4(hw[0], hw[1], hw[2], hw[3]);
            *reinterpret_cast<uint4*>(&hlo[(size_t)n * 256 + fbase]) =
                make_uint4(lw[0], lw[1], lw[2], lw[3]);
        } else {
            h16x8 o;
            #pragma unroll
            for (int j = 0; j < 8; ++j) o[j] = (_Float16)acc[j];
            *reinterpret_cast<h16x8*>(&hfin[(size_t)n * 256 + fbase]) = o;
        }
    }

    if (MODE == 0) {
        // stats: reduce h and h^2 over the 16 node-slots (grp bits = lane 2..5)
        float s[8], q[8];
        #pragma unroll
        for (int j = 0; j < 8; ++j) { s[j] = acc[j]; q[j] = acc[j] * acc[j]; }
        #pragma unroll
        for (int m = 4; m <= 32; m <<= 1) {
            #pragma unroll
            for (int j = 0; j < 8; ++j) {
                s[j] += __shfl_xor(s[j], m, 64);
                q[j] += __shfl_xor(q[j], m, 64);
            }
        }
        if (grp == 0) {
            float* part = stats + (size_t)(blockIdx.x & (NPART - 1)) * 512;
            #pragma unroll
            for (int j = 0; j < 8; ++j) {
                atomicAdd(&part[fbase + j], s[j]);
                atomicAdd(&part[256 + fbase + j], q[j]);
            }
        }
    }
}

// ---------------- global_add_pool (run-length + atomics, fp16 input) ---------
template<int ROWS>
__global__ __launch_bounds__(256)
void k_pool(const _Float16* __restrict__ h, const int* __restrict__ batch,
            float* __restrict__ out) {
    const int f = threadIdx.x;
    const int r0 = blockIdx.x * ROWS;
    float acc = 0.f;
    int cur = -1;
    for (int i = 0; i < ROWS; ++i) {
        int n = r0 + i;
        if (n >= N_NODES) break;
        int g = batch[n];
        float v = (float)h[(size_t)n * F + f];
        if (g != cur) {
            if (cur >= 0) atomicAdd(&out[(size_t)cur * F + f], acc);
            cur = g; acc = v;
        } else {
            acc += v;
        }
    }
    if (cur >= 0) atomicAdd(&out[(size_t)cur * F + f], acc);
}

// ---------------- host ----------------
extern "C" void kernel_launch(void* const* d_in, const int* in_sizes, int n_in,
                              void* d_out, int out_size, void* d_ws, size_t ws_size,
                              hipStream_t stream) {
    const float* x     = (const float*)d_in[0];
    const int*   ei    = (const int*)d_in[1];
    const int*   batch = (const int*)d_in[2];
    const float* W[6], *bias[6], *gamma[5], *beta[5];
    for (int i = 0; i < 6; ++i) {
        W[i]    = (const float*)d_in[3 + 2 * i];
        bias[i] = (const float*)d_in[4 + 2 * i];
    }
    for (int i = 0; i < 5; ++i) {
        gamma[i] = (const float*)d_in[15 + 2 * i];
        beta[i]  = (const float*)d_in[16 + 2 * i];
    }
    float* out = (float*)d_out;

    char* ws = (char*)d_ws;
    size_t off = 0;
    auto alloc = [&](size_t bytes) {
        void* p = ws + off;
        off = (off + bytes + 255) & ~(size_t)255;
        return p;
    };
    int*   cnt      = (int*)  alloc(N_NODES * 4);
    int*   rowptr   = (int*)  alloc((N_NODES + 1) * 4);
    int*   fillptr  = (int*)  alloc(N_NODES * 4);
    int*   bsum     = (int*)  alloc(256 * 4);
    float* dinv     = (float*)alloc(N_NODES * 4);
    int2*  epair    = (int2*) alloc((size_t)N_EDGES * 8);
    float* rowvec   = (float*)alloc(F * 4);
    float* statsAll = (float*)alloc((size_t)5 * NPART * 512 * 4);   // 640 KB
    short* Whi[6]; short* Wlo[6];
    for (int l = 0; l < 6; ++l) {
        int K = (l == 0) ? 128 : 256;
        Whi[l] = (short*)alloc((size_t)256 * K * 2);
        Wlo[l] = (short*)alloc((size_t)256 * K * 2);
    }
    short* xhi = (short*)alloc((size_t)N_NODES * 128 * 2);   // 12.8 MB
    short* xlo = (short*)alloc((size_t)N_NODES * 128 * 2);
    short* hhi = (short*)alloc((size_t)N_NODES * F * 2);     // 25.6 MB
    short* hlo = (short*)alloc((size_t)N_NODES * F * 2);
    _Float16* xw   = (_Float16*)alloc((size_t)N_NODES * F * 2);   // 25.6 MB
    _Float16* hfin = (_Float16*)alloc((size_t)N_NODES * F * 2);   // 25.6 MB

    const int* src = ei;
    const int* dst = ei + N_EDGES;

    // ---- CSR build + dinv + packs ----
    hipMemsetAsync(cnt, 0, N_NODES * 4, stream);
    hipMemsetAsync(out, 0, (size_t)N_GRAPHS * F * 4, stream);
    hipMemsetAsync(rowvec, 0, F * 4, stream);                     // layer-1 rowvec = 0
    hipMemsetAsync(statsAll, 0, (size_t)5 * NPART * 512 * 4, stream);
    k_hist<<<(N_EDGES / 4 + 255) / 256, 256, 0, stream>>>(dst, cnt);
    k_dinv<<<(N_NODES + 255) / 256, 256, 0, stream>>>(cnt, dinv);
    k_scan1<<<SCAN_BLOCKS, 256, 0, stream>>>(cnt, rowptr, bsum);
    k_scan2<<<1, 256, 0, stream>>>(bsum);
    k_scan3<<<SCAN_BLOCKS, 256, 0, stream>>>(rowptr, bsum);
    hipMemcpyAsync(fillptr, rowptr, N_NODES * 4, hipMemcpyDeviceToDevice, stream);
    k_scatter<<<(N_EDGES / 4 + 255) / 256, 256, 0, stream>>>(src, dst, dinv, fillptr, epair);
    k_pack<<<(256 * 128 + 255) / 256, 256, 0, stream>>>(W[0], Whi[0], Wlo[0], 128);
    k_splitx<<<(N_NODES * 32 + 255) / 256, 256, 0, stream>>>(x, xhi, xlo);

    const int aggGrid = NCHUNK * NODE_BLOCKS;   // 6256
    for (int l = 0; l < 6; ++l) {
        const int K = (l == 0) ? 128 : 256;
        const short* Ah = (l == 0) ? xhi : hhi;
        const short* Al = (l == 0) ? xlo : hlo;
        k_gemm_mfma<<<784, 256, 0, stream>>>(Ah, Al, Whi[l], Wlo[l], xw, N_NODES, K);

        if (l < 5) {
            float* stats = statsAll + (size_t)l * NPART * 512;
            k_agg3<0><<<aggGrid, 256, 0, stream>>>(xw, dinv, rowptr, epair,
                                                   bias[l], rowvec, hhi, hlo,
                                                   nullptr, stats);
            k_wfold<<<256, 256, 0, stream>>>(W[l + 1], stats, gamma[l], beta[l],
                                             Whi[l + 1], Wlo[l + 1], rowvec);
        } else {
            k_agg3<1><<<aggGrid, 256, 0, stream>>>(xw, dinv, rowptr, epair,
                                                   bias[l], rowvec, nullptr, nullptr,
                                                   hfin, nullptr);
            k_pool<128><<<(N_NODES + 127) / 128, 256, 0, stream>>>(hfin, batch, out);
        }
    }
}

// Round 10
// 1012.981 us; speedup vs baseline: 1.3793x; 1.3793x over previous
//
#include <hip/hip_runtime.h>

#define N_NODES 50000
#define N_EDGES 800000
#define N_GRAPHS 500
#define BN_EPS 1e-5f
#define F 256
#define SCAN_BLOCKS ((N_NODES + 255) / 256)   // 196
#define NPART 64                              // stats atomic partitions

typedef short short8 __attribute__((ext_vector_type(8)));
typedef short short4v __attribute__((ext_vector_type(4)));
typedef float f32x4 __attribute__((ext_vector_type(4)));
typedef _Float16 h16x8 __attribute__((ext_vector_type(8)));

#define AS1 __attribute__((address_space(1)))
#define AS3 __attribute__((address_space(3)))

// ---------------- degree histogram (4 edges/thread) ----------------
__global__ void k_hist(const int* __restrict__ dst, int* __restrict__ cnt) {
    int e0 = (blockIdx.x * blockDim.x + threadIdx.x) * 4;
    if (e0 >= N_EDGES) return;
    int4 d4 = *reinterpret_cast<const int4*>(&dst[e0]);
    atomicAdd(&cnt[d4.x], 1);
    atomicAdd(&cnt[d4.y], 1);
    atomicAdd(&cnt[d4.z], 1);
    atomicAdd(&cnt[d4.w], 1);
}

__global__ void k_dinv(const int* __restrict__ cnt, float* __restrict__ dinv) {
    int n = blockIdx.x * blockDim.x + threadIdx.x;
    if (n < N_NODES) dinv[n] = rsqrtf((float)cnt[n] + 1.0f);
}

// ---------------- prefix scan ----------------
__global__ void k_scan1(const int* __restrict__ cnt, int* __restrict__ rowptr,
                        int* __restrict__ bsum) {
    __shared__ int s[256];
    int tid = threadIdx.x;
    int i = blockIdx.x * 256 + tid;
    int v = (i < N_NODES) ? cnt[i] : 0;
    s[tid] = v;
    __syncthreads();
    for (int off = 1; off < 256; off <<= 1) {
        int add = (tid >= off) ? s[tid - off] : 0;
        __syncthreads();
        s[tid] += add;
        __syncthreads();
    }
    if (i < N_NODES) rowptr[i] = s[tid] - v;
    if (tid == 255) bsum[blockIdx.x] = s[255];
}

__global__ void k_scan2(int* __restrict__ bsum) {
    __shared__ int s[256];
    int tid = threadIdx.x;
    int v = (tid < SCAN_BLOCKS) ? bsum[tid] : 0;
    s[tid] = v;
    __syncthreads();
    for (int off = 1; off < 256; off <<= 1) {
        int add = (tid >= off) ? s[tid - off] : 0;
        __syncthreads();
        s[tid] += add;
        __syncthreads();
    }
    if (tid < SCAN_BLOCKS) bsum[tid] = s[tid] - v;
}

__global__ void k_scan3(int* __restrict__ rowptr, const int* __restrict__ bsum) {
    int i = blockIdx.x * 256 + threadIdx.x;
    if (i < N_NODES) rowptr[i] += bsum[blockIdx.x];
    if (i == 0) rowptr[N_NODES] = N_EDGES;
}

// ---------------- scatter edges into CSR (4 edges/thread) --------------------
__global__ void k_scatter(const int* __restrict__ src, const int* __restrict__ dst,
                          const float* __restrict__ dinv, int* __restrict__ fillptr,
                          int2* __restrict__ epair) {
    int e0 = (blockIdx.x * blockDim.x + threadIdx.x) * 4;
    if (e0 >= N_EDGES) return;
    int4 s4 = *reinterpret_cast<const int4*>(&src[e0]);
    int4 d4 = *reinterpret_cast<const int4*>(&dst[e0]);
    int ss[4] = {s4.x, s4.y, s4.z, s4.w};
    int dd[4] = {d4.x, d4.y, d4.z, d4.w};
    #pragma unroll
    for (int j = 0; j < 4; ++j) {
        float norm = dinv[ss[j]] * dinv[dd[j]];
        int slot = atomicAdd(&fillptr[dd[j]], 1);
        epair[slot] = make_int2(ss[j], __float_as_int(norm));
    }
}

// ---------------- W1 prepack (no BN): W[K][256] f32 -> [256][K] hi/lo bf16 ---
__global__ void k_pack(const float* __restrict__ W, short* __restrict__ hi,
                       short* __restrict__ lo, int K) {
    int idx = blockIdx.x * 256 + threadIdx.x;
    if (idx >= 256 * K) return;
    int n = idx / K, k = idx - n * K;
    float f = W[(size_t)k * 256 + n];
    unsigned u = __builtin_bit_cast(unsigned, f);
    hi[idx] = (short)(u >> 16);
    float hf = __builtin_bit_cast(float, u & 0xFFFF0000u);
    lo[idx] = (short)(__builtin_bit_cast(unsigned, f - hf) >> 16);
}

// ---------------- BN-finalize + weight fold in one kernel --------------------
__global__ __launch_bounds__(256)
void k_wfold(const float* __restrict__ W, const float* __restrict__ stats,
             const float* __restrict__ gamma, const float* __restrict__ beta,
             short* __restrict__ hi, short* __restrict__ lo,
             float* __restrict__ rowvec) {
    __shared__ float red[256];
    const int n = blockIdx.x;
    const int k = threadIdx.x;
    float s = 0.f, q = 0.f;
    for (int p = 0; p < NPART; ++p) {
        s += stats[(size_t)p * 512 + k];
        q += stats[(size_t)p * 512 + 256 + k];
    }
    float m = s * (1.0f / N_NODES);
    float var = q * (1.0f / N_NODES) - m * m;
    float mulk = gamma[k] * rsqrtf(var + BN_EPS);
    float addk = beta[k] - m * mulk;
    float w = W[(size_t)k * 256 + n];
    float f = w * mulk;
    unsigned u = __builtin_bit_cast(unsigned, f);
    hi[(size_t)n * 256 + k] = (short)(u >> 16);
    float hf = __builtin_bit_cast(float, u & 0xFFFF0000u);
    lo[(size_t)n * 256 + k] = (short)(__builtin_bit_cast(unsigned, f - hf) >> 16);
    red[k] = addk * w;
    __syncthreads();
    for (int off = 128; off > 0; off >>= 1) {
        if (k < off) red[k] += red[k + off];
        __syncthreads();
    }
    if (k == 0) rowvec[n] = red[0];
}

// ---------------- split x (layer-1 input) into bf16 hi/lo -------------------
__global__ void k_splitx(const float* __restrict__ x, short* __restrict__ hi,
                         short* __restrict__ lo) {
    int idx = blockIdx.x * 256 + threadIdx.x;   // over N_NODES*128/4
    if (idx >= N_NODES * 32) return;
    float4 v = reinterpret_cast<const float4*>(x)[idx];
    float vv[4] = {v.x, v.y, v.z, v.w};
    short4v h4, l4;
    #pragma unroll
    for (int j = 0; j < 4; ++j) {
        unsigned u = __builtin_bit_cast(unsigned, vv[j]);
        h4[j] = (short)(u >> 16);
        float hf = __builtin_bit_cast(float, u & 0xFFFF0000u);
        l4[j] = (short)(__builtin_bit_cast(unsigned, vv[j] - hf) >> 16);
    }
    *reinterpret_cast<short4v*>(&hi[(size_t)idx * 4]) = h4;
    *reinterpret_cast<short4v*>(&lo[(size_t)idx * 4]) = l4;
}

// ---------------- split-bf16 MFMA GEMM with global_load_lds A-staging --------
// LDS layout per (buf,part): [instr j(2)][wave(4)][lane(64)] x 16B, linear dest.
// Lane l of wave w, instr j sources row = w*32+(l&31), 16B-unit u=(j<<1)|(l>>5)
// -> fragment read (row, u=lane>>4) lands 16 consecutive rows on 16 distinct
// 16B slots (conflict-free by source pre-swizzle; LDS dest stays linear).
#define BK 32
__global__ __launch_bounds__(256)
void k_gemm_mfma(const short* __restrict__ Ahi, const short* __restrict__ Alo,
                 const short* __restrict__ Bhi, const short* __restrict__ Blo,
                 _Float16* __restrict__ C, int M, int K) {
    __shared__ unsigned As[2][2][2][4][256];   // [buf][part][j][wave][lane*4] = 32KB
    const int tid  = threadIdx.x;
    const int lane = tid & 63;
    const int w    = tid >> 6;
    const int wr   = (w >> 1) * 64;
    const int wc   = (w & 1) * 64;
    const int bid  = blockIdx.x;
    const int bx   = (bid >> 4) * 8 + (bid & 7);
    const int by   = (bid >> 3) & 1;
    const int brow = bx * 128;
    const int bcol = by * 128;

    f32x4 acc[4][4];
    #pragma unroll
    for (int m = 0; m < 4; ++m)
        #pragma unroll
        for (int n = 0; n < 4; ++n) acc[m][n] = (f32x4){0.f, 0.f, 0.f, 0.f};

    const int NS = K / BK;
    const int srow = (w << 5) + (lane & 31);          // staging source row
    const size_t srbase = (size_t)(brow + srow) * K;

    auto stage = [&](int s, int b) {
        #pragma unroll
        for (int j = 0; j < 2; ++j) {
            int u = (j << 1) | (lane >> 5);
            const short* gh = Ahi + srbase + (size_t)s * BK + u * 8;
            const short* gl = Alo + srbase + (size_t)s * BK + u * 8;
            __builtin_amdgcn_global_load_lds((const AS1 void*)gh,
                                             (AS3 void*)&As[b][0][j][w][0], 16, 0, 0);
            __builtin_amdgcn_global_load_lds((const AS1 void*)gl,
                                             (AS3 void*)&As[b][1][j][w][0], 16, 0, 0);
        }
    };

    stage(0, 0);
    __syncthreads();

    for (int s = 0; s < NS; ++s) {
        const int cur = s & 1;
        if (s + 1 < NS) stage(s + 1, cur ^ 1);   // DMA flies under the MFMAs

        short8 bh[4], bl[4];
        const int kb = s * BK + (lane >> 4) * 8;
        #pragma unroll
        for (int n = 0; n < 4; ++n) {
            int col = bcol + wc + n * 16 + (lane & 15);
            bh[n] = *reinterpret_cast<const short8*>(Bhi + (size_t)col * K + kb);
            bl[n] = *reinterpret_cast<const short8*>(Blo + (size_t)col * K + kb);
        }
        const int j    = lane >> 5;
        const int lsel = ((lane >> 4) & 1) << 5;
        #pragma unroll
        for (int m = 0; m < 4; ++m) {
            int row  = wr + m * 16 + (lane & 15);
            int wprm = (row >> 5) & 3;
            int lidx = (row & 31) | lsel;
            const unsigned* ph = &As[cur][0][j][wprm][lidx * 4];
            const unsigned* pl = &As[cur][1][j][wprm][lidx * 4];
            short8 ah = *reinterpret_cast<const short8*>(ph);
            short8 al = *reinterpret_cast<const short8*>(pl);
            #pragma unroll
            for (int n = 0; n < 4; ++n) {
                acc[m][n] = __builtin_amdgcn_mfma_f32_16x16x32_bf16(ah, bh[n], acc[m][n], 0, 0, 0);
                acc[m][n] = __builtin_amdgcn_mfma_f32_16x16x32_bf16(al, bh[n], acc[m][n], 0, 0, 0);
                acc[m][n] = __builtin_amdgcn_mfma_f32_16x16x32_bf16(ah, bl[n], acc[m][n], 0, 0, 0);
            }
        }
        __syncthreads();   // drains next-buf DMA; protects buf reuse
    }

    #pragma unroll
    for (int m = 0; m < 4; ++m) {
        #pragma unroll
        for (int n = 0; n < 4; ++n) {
            int col = bcol + wc + n * 16 + (lane & 15);
            #pragma unroll
            for (int j2 = 0; j2 < 4; ++j2) {
                int row = brow + wr + m * 16 + (lane >> 4) * 4 + j2;
                if (row < M) C[(size_t)row * 256 + col] = (_Float16)acc[m][n][j2];
            }
        }
    }
}

// ---------------- fused aggregation: one node per wave (round-8 structure) ---
// agg = sum(norm*xw[src]) + dinv^2*xw[n]; S = dinv^2 + sum(norm) in-register
// h = relu(agg + S*rowvec + bias)
// MODE 0: h -> bf16 hi/lo split + BN stats (partitioned atomics).
// MODE 1: h -> fp16 hfin (pooled by k_pool).
#define BATCH 8
template<int MODE>
__global__ __launch_bounds__(256)
void k_agg2(const _Float16* __restrict__ xw, const float* __restrict__ dinv,
            const int* __restrict__ rowptr, const int2* __restrict__ epair,
            const float* __restrict__ bias, const float* __restrict__ rowvec,
            short* __restrict__ hhi, short* __restrict__ hlo,
            _Float16* __restrict__ hfin, float* __restrict__ stats) {
    __shared__ float red[2][4][256];
    const int lane = threadIdx.x & 63;
    const int wave = threadIdx.x >> 6;
    const int half = lane >> 5;
    const int fl   = lane & 31;          // feature block: [8*fl, 8*fl+8)
    const int n    = blockIdx.x * 4 + wave;   // grid = 12500 exact

    const h16x8* xw8 = reinterpret_cast<const h16x8*>(xw);

    float acc[8];
    float wsum;
    if (half == 0) {
        float d = dinv[n];
        float sl = d * d;
        h16x8 sv = xw8[(size_t)n * 32 + fl];
        #pragma unroll
        for (int j = 0; j < 8; ++j) acc[j] = sl * (float)sv[j];
        wsum = sl;
    } else {
        #pragma unroll
        for (int j = 0; j < 8; ++j) acc[j] = 0.f;
        wsum = 0.f;
    }

    const int beg = rowptr[n], end = rowptr[n + 1];
    int i = beg + half;

    if (i < end) {
        int ecur[BATCH]; float wcur[BATCH];
        #pragma unroll
        for (int k = 0; k < BATCH; ++k) {
            int idx = i + 2 * k;
            bool ok = idx < end;
            int2 p = epair[ok ? idx : (end - 1)];
            ecur[k] = p.x;
            wcur[k] = ok ? __int_as_float(p.y) : 0.f;
        }
        while (true) {
            h16x8 r[BATCH];
            #pragma unroll
            for (int k = 0; k < BATCH; ++k)
                r[k] = xw8[(size_t)ecur[k] * 32 + fl];

            int inext = i + 2 * BATCH;
            bool more = inext < end;
            int enxt[BATCH]; float wnxt[BATCH];
            if (more) {
                #pragma unroll
                for (int k = 0; k < BATCH; ++k) {
                    int idx = inext + 2 * k;
                    bool ok = idx < end;
                    int2 p = epair[ok ? idx : (end - 1)];
                    enxt[k] = p.x;
                    wnxt[k] = ok ? __int_as_float(p.y) : 0.f;
                }
            }
            #pragma unroll
            for (int k = 0; k < BATCH; ++k) {
                wsum += wcur[k];
                #pragma unroll
                for (int j = 0; j < 8; ++j)
                    acc[j] = fmaf(wcur[k], (float)r[k][j], acc[j]);
            }
            if (!more) break;
            i = inext;
            #pragma unroll
            for (int k = 0; k < BATCH; ++k) { ecur[k] = enxt[k]; wcur[k] = wnxt[k]; }
        }
    }

    // merge halves
    #pragma unroll
    for (int j = 0; j < 8; ++j) acc[j] += __shfl_xor(acc[j], 32, 64);
    wsum += __shfl_xor(wsum, 32, 64);

    if (half == 0) {
        float4 b0 = *reinterpret_cast<const float4*>(&bias[fl * 8]);
        float4 b1 = *reinterpret_cast<const float4*>(&bias[fl * 8 + 4]);
        float4 r0 = *reinterpret_cast<const float4*>(&rowvec[fl * 8]);
        float4 r1 = *reinterpret_cast<const float4*>(&rowvec[fl * 8 + 4]);
        float bv[8] = {b0.x, b0.y, b0.z, b0.w, b1.x, b1.y, b1.z, b1.w};
        float rv[8] = {r0.x, r0.y, r0.z, r0.w, r1.x, r1.y, r1.z, r1.w};
        #pragma unroll
        for (int j = 0; j < 8; ++j)
            acc[j] = fmaxf(acc[j] + fmaf(wsum, rv[j], bv[j]), 0.f);

        if (MODE == 0) {
            unsigned hw[4], lw[4];
            #pragma unroll
            for (int p = 0; p < 4; ++p) {
                float f0 = acc[2 * p], f1 = acc[2 * p + 1];
                unsigned u0 = __builtin_bit_cast(unsigned, f0);
                unsigned u1 = __builtin_bit_cast(unsigned, f1);
                hw[p] = (u1 & 0xFFFF0000u) | (u0 >> 16);
                float h0 = __builtin_bit_cast(float, u0 & 0xFFFF0000u);
                float h1 = __builtin_bit_cast(float, u1 & 0xFFFF0000u);
                lw[p] = (__builtin_bit_cast(unsigned, f1 - h1) & 0xFFFF0000u) |
                        (__builtin_bit_cast(unsigned, f0 - h0) >> 16);
            }
            *reinterpret_cast<uint4*>(&hhi[(size_t)n * 256 + fl * 8]) =
                make_uint4(hw[0], hw[1], hw[2], hw[3]);
            *reinterpret_cast<uint4*>(&hlo[(size_t)n * 256 + fl * 8]) =
                make_uint4(lw[0], lw[1], lw[2], lw[3]);
            float4 o0 = make_float4(acc[0], acc[1], acc[2], acc[3]);
            float4 o1 = make_float4(acc[4], acc[5], acc[6], acc[7]);
            float4 q0 = make_float4(acc[0]*acc[0], acc[1]*acc[1], acc[2]*acc[2], acc[3]*acc[3]);
            float4 q1 = make_float4(acc[4]*acc[4], acc[5]*acc[5], acc[6]*acc[6], acc[7]*acc[7]);
            *reinterpret_cast<float4*>(&red[0][wave][fl * 8])     = o0;
            *reinterpret_cast<float4*>(&red[0][wave][fl * 8 + 4]) = o1;
            *reinterpret_cast<float4*>(&red[1][wave][fl * 8])     = q0;
            *reinterpret_cast<float4*>(&red[1][wave][fl * 8 + 4]) = q1;
        } else {
            h16x8 o;
            #pragma unroll
            for (int j = 0; j < 8; ++j) o[j] = (_Float16)acc[j];
            *reinterpret_cast<h16x8*>(&hfin[(size_t)n * 256 + fl * 8]) = o;
        }
    }

    if (MODE == 0) {
        __syncthreads();
        int t = threadIdx.x;
        float s = red[0][0][t] + red[0][1][t] + red[0][2][t] + red[0][3][t];
        float q = red[1][0][t] + red[1][1][t] + red[1][2][t] + red[1][3][t];
        float* part = stats + (size_t)(blockIdx.x & (NPART - 1)) * 512;
        atomicAdd(&part[t], s);
        atomicAdd(&part[256 + t], q);
    }
}

// ---------------- global_add_pool (run-length + atomics, fp16 input) ---------
template<int ROWS>
__global__ __launch_bounds__(256)
void k_pool(const _Float16* __restrict__ h, const int* __restrict__ batch,
            float* __restrict__ out) {
    const int f = threadIdx.x;
    const int r0 = blockIdx.x * ROWS;
    float acc = 0.f;
    int cur = -1;
    for (int i = 0; i < ROWS; ++i) {
        int n = r0 + i;
        if (n >= N_NODES) break;
        int g = batch[n];
        float v = (float)h[(size_t)n * F + f];
        if (g != cur) {
            if (cur >= 0) atomicAdd(&out[(size_t)cur * F + f], acc);
            cur = g; acc = v;
        } else {
            acc += v;
        }
    }
    if (cur >= 0) atomicAdd(&out[(size_t)cur * F + f], acc);
}

// ---------------- host ----------------
extern "C" void kernel_launch(void* const* d_in, const int* in_sizes, int n_in,
                              void* d_out, int out_size, void* d_ws, size_t ws_size,
                              hipStream_t stream) {
    const float* x     = (const float*)d_in[0];
    const int*   ei    = (const int*)d_in[1];
    const int*   batch = (const int*)d_in[2];
    const float* W[6], *bias[6], *gamma[5], *beta[5];
    for (int i = 0; i < 6; ++i) {
        W[i]    = (const float*)d_in[3 + 2 * i];
        bias[i] = (const float*)d_in[4 + 2 * i];
    }
    for (int i = 0; i < 5; ++i) {
        gamma[i] = (const float*)d_in[15 + 2 * i];
        beta[i]  = (const float*)d_in[16 + 2 * i];
    }
    float* out = (float*)d_out;

    char* ws = (char*)d_ws;
    size_t off = 0;
    auto alloc = [&](size_t bytes) {
        void* p = ws + off;
        off = (off + bytes + 255) & ~(size_t)255;
        return p;
    };
    int*   cnt      = (int*)  alloc(N_NODES * 4);
    int*   rowptr   = (int*)  alloc((N_NODES + 1) * 4);
    int*   fillptr  = (int*)  alloc(N_NODES * 4);
    int*   bsum     = (int*)  alloc(256 * 4);
    float* dinv     = (float*)alloc(N_NODES * 4);
    int2*  epair    = (int2*) alloc((size_t)N_EDGES * 8);
    float* rowvec   = (float*)alloc(F * 4);
    float* statsAll = (float*)alloc((size_t)5 * NPART * 512 * 4);   // 640 KB
    short* Whi[6]; short* Wlo[6];
    for (int l = 0; l < 6; ++l) {
        int K = (l == 0) ? 128 : 256;
        Whi[l] = (short*)alloc((size_t)256 * K * 2);
        Wlo[l] = (short*)alloc((size_t)256 * K * 2);
    }
    short* xhi = (short*)alloc((size_t)N_NODES * 128 * 2);   // 12.8 MB
    short* xlo = (short*)alloc((size_t)N_NODES * 128 * 2);
    short* hhi = (short*)alloc((size_t)N_NODES * F * 2);     // 25.6 MB
    short* hlo = (short*)alloc((size_t)N_NODES * F * 2);
    _Float16* xw   = (_Float16*)alloc((size_t)N_NODES * F * 2);   // 25.6 MB
    _Float16* hfin = (_Float16*)alloc((size_t)N_NODES * F * 2);   // 25.6 MB

    const int* src = ei;
    const int* dst = ei + N_EDGES;

    // ---- CSR build + dinv + packs ----
    hipMemsetAsync(cnt, 0, N_NODES * 4, stream);
    hipMemsetAsync(out, 0, (size_t)N_GRAPHS * F * 4, stream);
    hipMemsetAsync(rowvec, 0, F * 4, stream);                     // layer-1 rowvec = 0
    hipMemsetAsync(statsAll, 0, (size_t)5 * NPART * 512 * 4, stream);
    k_hist<<<(N_EDGES / 4 + 255) / 256, 256, 0, stream>>>(dst, cnt);
    k_dinv<<<(N_NODES + 255) / 256, 256, 0, stream>>>(cnt, dinv);
    k_scan1<<<SCAN_BLOCKS, 256, 0, stream>>>(cnt, rowptr, bsum);
    k_scan2<<<1, 256, 0, stream>>>(bsum);
    k_scan3<<<SCAN_BLOCKS, 256, 0, stream>>>(rowptr, bsum);
    hipMemcpyAsync(fillptr, rowptr, N_NODES * 4, hipMemcpyDeviceToDevice, stream);
    k_scatter<<<(N_EDGES / 4 + 255) / 256, 256, 0, stream>>>(src, dst, dinv, fillptr, epair);
    k_pack<<<(256 * 128 + 255) / 256, 256, 0, stream>>>(W[0], Whi[0], Wlo[0], 128);
    k_splitx<<<(N_NODES * 32 + 255) / 256, 256, 0, stream>>>(x, xhi, xlo);

    const int aggGrid = N_NODES / 4;     // 12500 blocks of 4 waves
    for (int l = 0; l < 6; ++l) {
        const int K = (l == 0) ? 128 : 256;
        const short* Ah = (l == 0) ? xhi : hhi;
        const short* Al = (l == 0) ? xlo : hlo;
        k_gemm_mfma<<<784, 256, 0, stream>>>(Ah, Al, Whi[l], Wlo[l], xw, N_NODES, K);

        if (l < 5) {
            float* stats = statsAll + (size_t)l * NPART * 512;
            k_agg2<0><<<aggGrid, 256, 0, stream>>>(xw, dinv, rowptr, epair,
                                                   bias[l], rowvec, hhi, hlo,
                                                   nullptr, stats);
            k_wfold<<<256, 256, 0, stream>>>(W[l + 1], stats, gamma[l], beta[l],
                                             Whi[l + 1], Wlo[l + 1], rowvec);
        } else {
            k_agg2<1><<<aggGrid, 256, 0, stream>>>(xw, dinv, rowptr, epair,
                                                   bias[l], rowvec, nullptr, nullptr,
                                                   hfin, nullptr);
            k_pool<128><<<(N_NODES + 127) / 128, 256, 0, stream>>>(hfin, batch, out);
        }
    }
}